// Round 1
// baseline (98.226 us; speedup 1.0000x reference)
//
#include <hip/hip_runtime.h>
#include <stdint.h>

// Problem constants (from reference): BS=16, T=16, N=512, C=128, E=128, OUT=256
// P = T*N = 8192, BT = BS*T = 256
// square[b,t,n,c] = feats[b, n*T+t, c]  (times == arange(P)%T, identical across batch)
// x1[bt][c][e] = sum_n square[n][c] * eig[e][n]
// x3[bt][o][e] = sum_c x1[c][e] * param[o][c][e]
// out[b][t*N+n][o] = relu( sum_e x3[o][e] * eig[e][n] )

typedef short bf16x8 __attribute__((ext_vector_type(8)));
typedef float f32x4 __attribute__((ext_vector_type(4)));

__device__ __forceinline__ ushort f2bf(float x) {
  uint32_t u = __float_as_uint(x);
  u += 0x7fffu + ((u >> 16) & 1u);   // round-to-nearest-even
  return (ushort)(u >> 16);
}

// ---------------- prep: eig -> bf16 [e][n] and transposed [n][e] ----------------
__global__ __launch_bounds__(128) void k_prep_eig(const float* __restrict__ eig,
                                                  ushort* __restrict__ eig_bf,
                                                  ushort* __restrict__ eigT) {
  int bid = blockIdx.x, t = threadIdx.x;
  if (bid < 512) {              // one block per n: coalesced eigT row write
    int n = bid;
    eigT[n * 128 + t] = f2bf(eig[t * 512 + n]);
  } else {                      // one block per e: coalesced eig_bf row
    int e = bid - 512;
#pragma unroll
    for (int i = 0; i < 4; ++i) {
      int n = t + i * 128;
      eig_bf[e * 512 + n] = f2bf(eig[e * 512 + n]);
    }
  }
}

// ---------------- prep: paramT[e][o][c] = bf16(param[o][c][e]) ----------------
__global__ __launch_bounds__(256) void k_prep_param(const float* __restrict__ param,
                                                    ushort* __restrict__ paramT) {
  int o = blockIdx.x;
  int c = threadIdx.x & 127, h = threadIdx.x >> 7;
#pragma unroll 4
  for (int ee = 0; ee < 64; ++ee) {
    int e = h * 64 + ee;
    // write coalesced (c fast); reads L1-cached across the e-loop
    paramT[(size_t)e * 32768 + o * 128 + c] = f2bf(param[(size_t)o * 16384 + c * 128 + e]);
  }
}

// ---------------- stage 1: x1[e][bt][c] (bf16) ----------------
// per block (one bt): X1 = square^T (C x N) @ eig^T (N x E), K = n in chunks of 64
__global__ __launch_bounds__(256) void k_stage1(const float* __restrict__ feats,
                                                const ushort* __restrict__ eig_bf,
                                                ushort* __restrict__ x1) {
  int bt = blockIdx.x;
  int b = bt >> 4, tt = bt & 15;
  __shared__ ushort As[128 * 72];  // [c][n-chunk 64, pad 72] (transposed feats)
  __shared__ ushort Bs[128 * 72];  // [e][n-chunk 64, pad 72]
  int tid = threadIdx.x, l = tid & 63, w = tid >> 6;
  int wr = (w & 1) * 64;   // c offset of this wave's 64x64 tile
  int wc = (w >> 1) * 64;  // e offset
  int lr = l & 15, lg = l >> 4;
  f32x4 acc[4][4] = {};
  const float* fbase = feats + (size_t)b * (8192 * 128) + (size_t)tt * 128;

  for (int nc = 0; nc < 8; ++nc) {
    int n0 = nc * 64;
    // ---- stage A (transpose feats chunk into As[c][n]) ----
    {
      int nl = w * 16 + lr;                 // 0..63 (wave owns 16 rows)
      int cg = lg * 4;                      // 0,4,8,12
      const float* rowp = fbase + (size_t)(n0 + nl) * (16 * 128);
#pragma unroll
      for (int i = 0; i < 8; ++i) {
        int c0 = cg + i * 16;
        float4 v = *(const float4*)(rowp + c0);
        As[(c0 + 0) * 72 + nl] = f2bf(v.x);
        As[(c0 + 1) * 72 + nl] = f2bf(v.y);
        As[(c0 + 2) * 72 + nl] = f2bf(v.z);
        As[(c0 + 3) * 72 + nl] = f2bf(v.w);
      }
    }
    // ---- stage B (eig_bf rows, linear) ----
    {
      int part = tid & 7;   // 8 x 16B = 128B row segment
      int er = tid >> 3;    // 32 rows per pass
#pragma unroll
      for (int p = 0; p < 4; ++p) {
        int e = er + p * 32;
        uint4 v = *(const uint4*)(eig_bf + (size_t)e * 512 + n0 + part * 8);
        *(uint4*)&Bs[e * 72 + part * 8] = v;
      }
    }
    __syncthreads();
    // ---- compute ----
#pragma unroll
    for (int kk = 0; kk < 64; kk += 32) {
      bf16x8 af[4], bg[4];
#pragma unroll
      for (int fm = 0; fm < 4; ++fm)
        af[fm] = *(const bf16x8*)&As[(wr + fm * 16 + lr) * 72 + kk + lg * 8];
#pragma unroll
      for (int fn = 0; fn < 4; ++fn)
        bg[fn] = *(const bf16x8*)&Bs[(wc + fn * 16 + lr) * 72 + kk + lg * 8];
#pragma unroll
      for (int fm = 0; fm < 4; ++fm)
#pragma unroll
        for (int fn = 0; fn < 4; ++fn)
          acc[fm][fn] = __builtin_amdgcn_mfma_f32_16x16x32_bf16(af[fm], bg[fn], acc[fm][fn], 0, 0, 0);
    }
    __syncthreads();
  }
  // ---- epilogue: x1[e][bt][c], 8B packed stores ----
#pragma unroll
  for (int fm = 0; fm < 4; ++fm) {
    int c = wr + fm * 16 + lg * 4;
#pragma unroll
    for (int fn = 0; fn < 4; ++fn) {
      int e = wc + fn * 16 + lr;
      ushort4 pk;
      pk.x = f2bf(acc[fm][fn][0]);
      pk.y = f2bf(acc[fm][fn][1]);
      pk.z = f2bf(acc[fm][fn][2]);
      pk.w = f2bf(acc[fm][fn][3]);
      *(ushort4*)(x1 + (size_t)e * 32768 + bt * 128 + c) = pk;
    }
  }
}

// ---------------- stage 2: x3[bt][o][e] (bf16) ----------------
// grid: (btb 0..3) x (ob 0..3) x (ec 0..15); block does 8 e-slices of (bt64 x o64 over c128)
__global__ __launch_bounds__(256) void k_stage2(const ushort* __restrict__ x1,
                                                const ushort* __restrict__ paramT,
                                                ushort* __restrict__ x3) {
  int bx = blockIdx.x;
  int btb = bx & 3, ob = (bx >> 2) & 3, ec = bx >> 4;
  int bt0 = btb * 64, o0 = ob * 64, e0 = ec * 8;
  __shared__ ushort As[64 * 136];  // [bt][c pad 136]
  __shared__ ushort Bs[64 * 136];  // [o][c pad 136]
  int tid = threadIdx.x, l = tid & 63, w = tid >> 6;
  int wbt = (w & 1) * 32, wo = (w >> 1) * 32;
  int lr = l & 15, lg = l >> 4;

#pragma unroll
  for (int eh = 0; eh < 2; ++eh) {
    float res[2][2][4][4];
#pragma unroll
    for (int ei = 0; ei < 4; ++ei) {
      int e = e0 + eh * 4 + ei;
      {
        int part = tid & 15, row = tid >> 4;  // 16 rows/pass, 4 passes
#pragma unroll
        for (int p = 0; p < 4; ++p) {
          int r_ = row + p * 16;
          uint4 va = *(const uint4*)(x1 + (size_t)e * 32768 + (bt0 + r_) * 128 + part * 8);
          *(uint4*)&As[r_ * 136 + part * 8] = va;
          uint4 vb = *(const uint4*)(paramT + (size_t)e * 32768 + (o0 + r_) * 128 + part * 8);
          *(uint4*)&Bs[r_ * 136 + part * 8] = vb;
        }
      }
      __syncthreads();
      f32x4 acc[2][2] = {};
#pragma unroll
      for (int kk = 0; kk < 128; kk += 32) {
        bf16x8 af[2], bg[2];
#pragma unroll
        for (int fm = 0; fm < 2; ++fm)
          af[fm] = *(const bf16x8*)&As[(wbt + fm * 16 + lr) * 136 + kk + lg * 8];
#pragma unroll
        for (int fn = 0; fn < 2; ++fn)
          bg[fn] = *(const bf16x8*)&Bs[(wo + fn * 16 + lr) * 136 + kk + lg * 8];
#pragma unroll
        for (int fm = 0; fm < 2; ++fm)
#pragma unroll
          for (int fn = 0; fn < 2; ++fn)
            acc[fm][fn] = __builtin_amdgcn_mfma_f32_16x16x32_bf16(af[fm], bg[fn], acc[fm][fn], 0, 0, 0);
      }
      __syncthreads();
#pragma unroll
      for (int fm = 0; fm < 2; ++fm)
#pragma unroll
        for (int fn = 0; fn < 2; ++fn)
#pragma unroll
          for (int r = 0; r < 4; ++r) res[fm][fn][r][ei] = acc[fm][fn][r];
    }
    // pack 4 e's -> 8B stores into x3[bt][o][e]
#pragma unroll
    for (int fm = 0; fm < 2; ++fm) {
      int btl = bt0 + wbt + fm * 16 + lg * 4;
#pragma unroll
      for (int fn = 0; fn < 2; ++fn) {
        int o = o0 + wo + fn * 16 + lr;
#pragma unroll
        for (int r = 0; r < 4; ++r) {
          ushort4 pk;
          pk.x = f2bf(res[fm][fn][r][0]);
          pk.y = f2bf(res[fm][fn][r][1]);
          pk.z = f2bf(res[fm][fn][r][2]);
          pk.w = f2bf(res[fm][fn][r][3]);
          *(ushort4*)(x3 + (size_t)(btl + r) * 32768 + o * 128 + e0 + eh * 4) = pk;
        }
      }
    }
  }
}

// ---------------- stage 3: out[bt][n][o] = relu( x3[o][e] @ eigT[n][e]^T ) ----------------
// M = o (128 per block), col = n (128 per block), K = e (128, 2 chunks of 64)
__global__ __launch_bounds__(256) void k_stage3(const ushort* __restrict__ x3,
                                                const ushort* __restrict__ eigT,
                                                float* __restrict__ out) {
  int bx = blockIdx.x;
  int bt = bx & 255, ob = (bx >> 8) & 1, nb = bx >> 9;
  int o0 = ob * 128, n0 = nb * 128;
  __shared__ ushort As[128 * 72];  // [o][e-chunk 64 pad 72]
  __shared__ ushort Bs[128 * 72];  // [n][e-chunk 64 pad 72]
  int tid = threadIdx.x, l = tid & 63, w = tid >> 6;
  int wo = (w & 1) * 64, wn = (w >> 1) * 64;
  int lr = l & 15, lg = l >> 4;
  f32x4 acc[4][4] = {};

#pragma unroll
  for (int ch = 0; ch < 2; ++ch) {
    int e0 = ch * 64;
    {
      int part = tid & 7, row = tid >> 3;  // 32 rows/pass, 4 passes
#pragma unroll
      for (int p = 0; p < 4; ++p) {
        int r_ = row + p * 32;
        uint4 va = *(const uint4*)(x3 + (size_t)bt * 32768 + (o0 + r_) * 128 + e0 + part * 8);
        *(uint4*)&As[r_ * 72 + part * 8] = va;
        uint4 vb = *(const uint4*)(eigT + (size_t)(n0 + r_) * 128 + e0 + part * 8);
        *(uint4*)&Bs[r_ * 72 + part * 8] = vb;
      }
    }
    __syncthreads();
#pragma unroll
    for (int kk = 0; kk < 64; kk += 32) {
      bf16x8 af[4], bg[4];
#pragma unroll
      for (int fm = 0; fm < 4; ++fm)
        af[fm] = *(const bf16x8*)&As[(wo + fm * 16 + lr) * 72 + kk + lg * 8];
#pragma unroll
      for (int fn = 0; fn < 4; ++fn)
        bg[fn] = *(const bf16x8*)&Bs[(wn + fn * 16 + lr) * 72 + kk + lg * 8];
#pragma unroll
      for (int fm = 0; fm < 4; ++fm)
#pragma unroll
        for (int fn = 0; fn < 4; ++fn)
          acc[fm][fn] = __builtin_amdgcn_mfma_f32_16x16x32_bf16(af[fm], bg[fn], acc[fm][fn], 0, 0, 0);
    }
    __syncthreads();
  }
  // epilogue: relu + f32 stores, o-contiguous float4
#pragma unroll
  for (int fm = 0; fm < 4; ++fm) {
    int o = o0 + wo + fm * 16 + lg * 4;
#pragma unroll
    for (int fn = 0; fn < 4; ++fn) {
      int n = n0 + wn + fn * 16 + lr;
      float4 v;
      v.x = fmaxf(acc[fm][fn][0], 0.f);
      v.y = fmaxf(acc[fm][fn][1], 0.f);
      v.z = fmaxf(acc[fm][fn][2], 0.f);
      v.w = fmaxf(acc[fm][fn][3], 0.f);
      *(float4*)(out + (size_t)bt * 131072 + (size_t)n * 256 + o) = v;
    }
  }
}

extern "C" void kernel_launch(void* const* d_in, const int* in_sizes, int n_in,
                              void* d_out, int out_size, void* d_ws, size_t ws_size,
                              hipStream_t stream) {
  const float* feats = (const float*)d_in[0];
  // d_in[1] = pos (unused), d_in[2] = times (statically arange%T), d_in[3] = ids (unused)
  const float* eig = (const float*)d_in[4];
  const float* param = (const float*)d_in[5];
  float* out = (float*)d_out;

  char* ws = (char*)d_ws;
  // workspace layout (total ~33.8 MB)
  ushort* paramT = (ushort*)(ws);                 // 8,388,608 B  [e][o][c]
  ushort* eig_bf = (ushort*)(ws + 8388608);       //   131,072 B  [e][n]
  ushort* eigT   = (ushort*)(ws + 8519680);       //   131,072 B  [n][e]
  ushort* x1     = (ushort*)(ws + 8650752);       // 8,388,608 B  [e][bt][c]
  ushort* x3     = (ushort*)(ws + 17039360);      // 16,777,216 B [bt][o][e]

  hipLaunchKernelGGL(k_prep_eig, dim3(640), dim3(128), 0, stream, eig, eig_bf, eigT);
  hipLaunchKernelGGL(k_prep_param, dim3(256), dim3(256), 0, stream, param, paramT);
  hipLaunchKernelGGL(k_stage1, dim3(256), dim3(256), 0, stream, feats, eig_bf, x1);
  hipLaunchKernelGGL(k_stage2, dim3(256), dim3(256), 0, stream, x1, paramT, x3);
  hipLaunchKernelGGL(k_stage3, dim3(2048), dim3(256), 0, stream, x3, eigT, out);
}